// Round 16
// baseline (340.720 us; speedup 1.0000x reference)
//
#include <hip/hip_runtime.h>
#include <hip/hip_bf16.h>
#include <math.h>

// Problem constants: N=50000, E=800000, D=64, K=500, C=64
#define DD 64
#define KK 500
#define KPAD 512
#define NPAD 50048   // N padded to multiple of 64
#define NS 50176     // N padded to multiple of 256 buckets (196*256)
#define SLOTS 128    // slotted-CSR capacity per node
#define NBUCK 196    // node buckets of 256 nodes each (196*256 = 50176)
#define BCAP 6144    // per-bucket edge capacity (mean 4096, sigma 64 -> +32 sigma)

typedef __attribute__((ext_vector_type(8))) short bf16x8;
typedef __attribute__((ext_vector_type(4))) float f32x4;

#if defined(__has_builtin)
#if __has_builtin(__builtin_amdgcn_cvt_pk_f32_fp8) && __has_builtin(__builtin_amdgcn_cvt_pk_fp8_f32)
#define HAS_FP8_CVT 1
#endif
#if __has_builtin(__builtin_amdgcn_exp2f)
#define EXP2(x) __builtin_amdgcn_exp2f(x)
#endif
#endif
#ifndef EXP2
#define EXP2(x) exp2f(x)
#endif

// final scale for fp8 accumulation (decode scale deferred in the no-builtin path)
#ifdef HAS_FP8_CVT
#define F8_INV (1.0f / 256.f)
#else
#define F8_INV 0x1p112f
#endif

__device__ inline unsigned short f2bf(float f) {
    unsigned u = __float_as_uint(f);
    u += 0x7fffu + ((u >> 16) & 1u);          // RNE
    return (unsigned short)(u >> 16);
}
__device__ inline unsigned packbf(float lo, float hi) {
    return ((unsigned)f2bf(hi) << 16) | (unsigned)f2bf(lo);
}
__device__ inline float bf2f(unsigned short h) {
    return __uint_as_float((unsigned)h << 16);
}

// async global->LDS, 16B per lane; LDS dest = uniform base + lane*16
__device__ inline void gload_lds16(const void* g, void* l) {
    __builtin_amdgcn_global_load_lds(
        (const __attribute__((address_space(1))) unsigned int*)g,
        (__attribute__((address_space(3))) unsigned int*)l, 16, 0, 0);
}

#ifndef HAS_FP8_CVT
// fp8 e4m3 bits -> f32 scaled by 2^-120 (exponent rebias via bit placement; exact incl. subnormals)
__device__ inline float f8bits(unsigned b) {
    return __uint_as_float(((b & 0x80u) << 24) | ((b & 0x7fu) << 20));
}
__device__ inline unsigned f32_to_fp8_slow(float f) {
    unsigned sgn = (__float_as_uint(f) >> 24) & 0x80u;
    float af = fabsf(f);
    if (!(af > 0.f)) return sgn;
    if (af >= 448.f) return sgn | 0x7E;
    int e; frexpf(af, &e);
    int E = e - 1 + 7;
    if (E < 1) { unsigned q = (unsigned)rintf(ldexpf(af, 9)); return sgn | q; }
    unsigned q = (unsigned)rintf(ldexpf(af, 10 - E));
    if (q >= 16) { q = 8; E++; }
    if (E > 15 || (E == 15 && q - 8 >= 7)) return sgn | 0x7E;
    return sgn | ((unsigned)E << 3) | (q - 8);
}
#endif

// 16 fp8 values (uint4) -> a[0..15]
__device__ inline void accf8v4(float* a, uint4 v) {
#ifdef HAS_FP8_CVT
    auto f0 = __builtin_amdgcn_cvt_pk_f32_fp8(v.x, false);
    a[0] += f0[0]; a[1] += f0[1];
    auto f1 = __builtin_amdgcn_cvt_pk_f32_fp8(v.x, true);
    a[2] += f1[0]; a[3] += f1[1];
    auto f2 = __builtin_amdgcn_cvt_pk_f32_fp8(v.y, false);
    a[4] += f2[0]; a[5] += f2[1];
    auto f3 = __builtin_amdgcn_cvt_pk_f32_fp8(v.y, true);
    a[6] += f3[0]; a[7] += f3[1];
    auto f4 = __builtin_amdgcn_cvt_pk_f32_fp8(v.z, false);
    a[8] += f4[0]; a[9] += f4[1];
    auto f5 = __builtin_amdgcn_cvt_pk_f32_fp8(v.z, true);
    a[10] += f5[0]; a[11] += f5[1];
    auto f6 = __builtin_amdgcn_cvt_pk_f32_fp8(v.w, false);
    a[12] += f6[0]; a[13] += f6[1];
    auto f7 = __builtin_amdgcn_cvt_pk_f32_fp8(v.w, true);
    a[14] += f7[0]; a[15] += f7[1];
#else
    a[0]  += f8bits(v.x & 0xff);         a[1]  += f8bits((v.x >> 8) & 0xff);
    a[2]  += f8bits((v.x >> 16) & 0xff); a[3]  += f8bits((v.x >> 24) & 0xff);
    a[4]  += f8bits(v.y & 0xff);         a[5]  += f8bits((v.y >> 8) & 0xff);
    a[6]  += f8bits((v.y >> 16) & 0xff); a[7]  += f8bits((v.y >> 24) & 0xff);
    a[8]  += f8bits(v.z & 0xff);         a[9]  += f8bits((v.z >> 8) & 0xff);
    a[10] += f8bits((v.z >> 16) & 0xff); a[11] += f8bits((v.z >> 24) & 0xff);
    a[12] += f8bits(v.w & 0xff);         a[13] += f8bits((v.w >> 8) & 0xff);
    a[14] += f8bits((v.w >> 16) & 0xff); a[15] += f8bits((v.w >> 24) & 0xff);
#endif
}

// 4 bf16 values (uint2) -> a[0..3]
__device__ inline void accbf4(float* a, uint2 v) {
    a[0] += __uint_as_float(v.x << 16);
    a[1] += __uint_as_float(v.x & 0xffff0000u);
    a[2] += __uint_as_float(v.y << 16);
    a[3] += __uint_as_float(v.y & 0xffff0000u);
}

// ---------------- phase A: bin edges by col-bucket and row-bucket ----------------
__global__ void __launch_bounds__(256) binA_kernel(
        const int* __restrict__ rowv, const int* __restrict__ colv,
        int* __restrict__ bcurC, int* __restrict__ bcurR,
        int* __restrict__ bstoreC, unsigned char* __restrict__ bstoreR, int E) {
    __shared__ int hc[NBUCK], hr[NBUCK], baseC[NBUCK], baseR[NBUCK];
    int t = threadIdx.x;
    if (t < NBUCK) { hc[t] = 0; hr[t] = 0; }
    __syncthreads();
    int e0 = blockIdx.x * 1024 + t * 4;
    int r[4], c[4];
#pragma unroll
    for (int i = 0; i < 4; ++i) {
        int e = e0 + i;
        if (e < E) {
            r[i] = rowv[e];
            c[i] = colv[e];
            atomicAdd(&hc[c[i] >> 8], 1);
            atomicAdd(&hr[r[i] >> 8], 1);
        } else {
            r[i] = -1; c[i] = -1;
        }
    }
    __syncthreads();
    if (t < NBUCK) {
        baseC[t] = atomicAdd(&bcurC[t], hc[t]);
        baseR[t] = atomicAdd(&bcurR[t], hr[t]);
        hc[t] = 0; hr[t] = 0;
    }
    __syncthreads();
#pragma unroll
    for (int i = 0; i < 4; ++i) {
        if (r[i] >= 0) {
            int bc = c[i] >> 8;
            int oc = baseC[bc] + atomicAdd(&hc[bc], 1);
            if (oc < BCAP) bstoreC[bc * BCAP + oc] = (r[i] << 8) | (c[i] & 255);
            int br = r[i] >> 8;
            int orr = baseR[br] + atomicAdd(&hr[br], 1);
            if (orr < BCAP) bstoreR[br * BCAP + orr] = (unsigned char)(r[i] & 255);
        }
    }
}

// ---------------- phase B1: build slotted CSR per bucket with LDS cursors ----------------
__global__ void __launch_bounds__(256) buildcsr_kernel(
        const int* __restrict__ bcurC, const int* __restrict__ bstoreC,
        int* __restrict__ esrc, int* __restrict__ degc, int n) {
    __shared__ int cur[256];
    int b = blockIdx.x, t = threadIdx.x;
    cur[t] = 0;
    __syncthreads();
    int cnt = min(bcurC[b], BCAP);
    const int* src = bstoreC + b * BCAP;
    for (int i = t; i < cnt; i += 256) {
        int packed = src[i];
        int cl = packed & 255, rr = packed >> 8;
        int p = atomicAdd(&cur[cl], 1);
        if (p < SLOTS) esrc[((size_t)(b * 256 + cl) << 7) + p] = rr;
    }
    __syncthreads();
    int node = b * 256 + t;
    if (node < n) degc[node] = min(cur[t], SLOTS);
}

// ---------------- phase B2: row degrees -> dinv ----------------
__global__ void __launch_bounds__(256) rowdeg_kernel(
        const int* __restrict__ bcurR, const unsigned char* __restrict__ bstoreR,
        float* __restrict__ dinv, int n) {
    __shared__ int cnt[256];
    int b = blockIdx.x, t = threadIdx.x;
    cnt[t] = 0;
    __syncthreads();
    int c = min(bcurR[b], BCAP);
    const unsigned char* src = bstoreR + b * BCAP;
    for (int i = t; i < c; i += 256) {
        atomicAdd(&cnt[src[i]], 1);
    }
    __syncthreads();
    int node = b * 256 + t;
    if (node < n) dinv[node] = 1.0f / sqrtf((float)(cnt[t] + 1));
}

// ---- fused prep: xb = bf16(dinv*x) + WaT/WeT transposes ----
__global__ void prep_kernel(const float* __restrict__ x, const float* __restrict__ dinv,
                            unsigned short* __restrict__ xb,
                            const float* __restrict__ Wa, const float* __restrict__ We,
                            unsigned short* __restrict__ WaT, unsigned short* __restrict__ WeT,
                            int n16) {
    int idx = blockIdx.x * blockDim.x + threadIdx.x;
    if (idx < n16) {
        int i = idx >> 4;
        float di = dinv[i];
        float4 v = ((const float4*)x)[idx];
        uint2 o;
        o.x = packbf(di * v.x, di * v.y);
        o.y = packbf(di * v.z, di * v.w);
        ((uint2*)xb)[idx] = o;
        return;
    }
    int j = idx - n16;
    if (j < KPAD * 64) {
        int c = j >> 6, d = j & 63;
        float v = (c < KK) ? Wa[(size_t)d * KK + c] : 0.f;
        WaT[j] = f2bf(v);
    } else if (j < (KPAD + DD) * 64) {
        int k = j - KPAD * 64;
        int c = k >> 6, d = k & 63;
        WeT[k] = f2bf(We[(size_t)d * 64 + c]);
    }
}

// ---- ub = bf16(xb[i] + sum_{in} xb[s]);  t[i] = dinv[i] + sum_{in} dinv[s] ----
// 16 lanes per edge (uint2 = 4 bf16 cols each), 4 edges in flight per load instr. (R11-proven)
__global__ void agg_kernel(const unsigned short* __restrict__ xb, const float* __restrict__ dinv,
                           const int* __restrict__ degc, const int* __restrict__ esrc,
                           float* __restrict__ t, unsigned short* __restrict__ ub, int n) {
    int wv = (blockIdx.x * blockDim.x + threadIdx.x) >> 6;
    int ln = threadIdx.x & 63;
    int g = ln >> 4, q = ln & 15;      // group 0..3 (edge slot), col chunk 0..15
    if (wv >= NPAD) return;
    if (wv >= n) {
        if (g == 0) ((uint2*)ub)[(size_t)wv * 16 + q] = make_uint2(0u, 0u);
        return;
    }
    const uint2* X2 = (const uint2*)xb;
    float ac[4] = {0.f, 0.f, 0.f, 0.f};
    float ts = 0.f;
    if (g == 0) {
        uint2 v = X2[(size_t)wv * 16 + q];   // self term, counted once
        accbf4(ac, v);
    }
    int p = wv << 7;
    int pend = p + degc[wv];
    for (; p + 7 < pend; p += 8) {
        int s0 = esrc[p + g];
        int s1 = esrc[p + 4 + g];
        uint2 v0 = X2[(size_t)s0 * 16 + q];
        uint2 v1 = X2[(size_t)s1 * 16 + q];
        float w0 = dinv[s0], w1 = dinv[s1];
        accbf4(ac, v0); accbf4(ac, v1);
        ts += w0 + w1;
    }
    for (; p + 3 < pend; p += 4) {
        int s = esrc[p + g];
        uint2 v = X2[(size_t)s * 16 + q];
        ts += dinv[s];
        accbf4(ac, v);
    }
    if (g < pend - p) {
        int s = esrc[p + g];
        uint2 v = X2[(size_t)s * 16 + q];
        ts += dinv[s];
        accbf4(ac, v);
    }
#pragma unroll
    for (int j = 0; j < 4; ++j) {
        ac[j] += __shfl_xor(ac[j], 16, 64);
        ac[j] += __shfl_xor(ac[j], 32, 64);
    }
    ts += __shfl_xor(ts, 16, 64);
    ts += __shfl_xor(ts, 32, 64);
    if (g == 0) {
        uint2 o;
        o.x = packbf(ac[0], ac[1]);
        o.y = packbf(ac[2], ac[3]);
        ((uint2*)ub)[(size_t)wv * 16 + q] = o;
        if (q == 0) t[wv] = dinv[wv] + ts;
    }
}

// ---- fused assign (MFMA, high-occupancy): block = 16 nodes, 4 waves split 512 clusters.
//      Softmax in exp2 domain (R15-proven: one v_exp_f32 per element). ----
#define F8ROW 520
#define LOG2E 1.44269504f
__global__ void __launch_bounds__(256) fused_s3_kernel(
        const unsigned short* __restrict__ ub, const unsigned short* __restrict__ WaT,
        const unsigned short* __restrict__ WeT,
        const float* __restrict__ ba, const float* __restrict__ be,
        const float* __restrict__ dinv, const float* __restrict__ tsum,
        unsigned short* __restrict__ S_T, unsigned char* __restrict__ Sf8,
        unsigned short* __restrict__ Z_T, int n) {
    __shared__ float bs[512];
    __shared__ float bes[64];
    __shared__ float wmax[4][16];
    __shared__ float wsum[4][16];
    __shared__ unsigned char f8[16 * F8ROW];
    int t = threadIdx.x;
    int n0 = blockIdx.x * 16;
    {
        float b0 = (t * 2     < KK) ? ba[t * 2]     : 0.f;
        float b1 = (t * 2 + 1 < KK) ? ba[t * 2 + 1] : 0.f;
        bs[t * 2] = b0; bs[t * 2 + 1] = b1;
        if (t < 64) bes[t] = be[t];
    }
    __syncthreads();
    int wv = t >> 6, ln = t & 63;
    int nl = ln & 15;
    int g  = ln >> 4;
    int node = n0 + nl;
    int kb = wv * 128;
    float sd = (node < n) ? dinv[node] : 0.f;
    float st = (node < n) ? tsum[node] : 0.f;
    const unsigned short* brow = ub + (size_t)node * 64;
    bf16x8 bf0 = *(const bf16x8*)&brow[g * 8];
    bf16x8 bf1 = *(const bf16x8*)&brow[32 + g * 8];
    f32x4 acc[8];
#pragma unroll
    for (int mt = 0; mt < 8; ++mt) {
        const unsigned short* arow = WaT + (size_t)(kb + mt * 16 + nl) * 64;
        bf16x8 af0 = *(const bf16x8*)&arow[g * 8];
        bf16x8 af1 = *(const bf16x8*)&arow[32 + g * 8];
        f32x4 a = __builtin_amdgcn_mfma_f32_16x16x32_bf16(af0, bf0, (f32x4){0.f,0.f,0.f,0.f}, 0, 0, 0);
        acc[mt] = __builtin_amdgcn_mfma_f32_16x16x32_bf16(af1, bf1, a, 0, 0, 0);
    }
    float sdl = sd * LOG2E;
    float m = -1e30f;
#pragma unroll
    for (int mt = 0; mt < 8; ++mt) {
#pragma unroll
        for (int r = 0; r < 4; ++r) {
            int cl = kb + mt * 16 + g * 4 + r;
            float L = sdl * (acc[mt][r] + st * bs[cl]);   // logit * log2(e)
            if (cl >= KK) L = -1e30f;
            acc[mt][r] = L;
            m = fmaxf(m, L);
        }
    }
    m = fmaxf(m, __shfl_xor(m, 16, 64));
    m = fmaxf(m, __shfl_xor(m, 32, 64));
    if (g == 0) wmax[wv][nl] = m;
    __syncthreads();
    m = fmaxf(fmaxf(wmax[0][nl], wmax[1][nl]), fmaxf(wmax[2][nl], wmax[3][nl]));
    float ssum = 0.f;
#pragma unroll
    for (int mt = 0; mt < 8; ++mt) {
#pragma unroll
        for (int r = 0; r < 4; ++r) {
            float e = EXP2(acc[mt][r] - m);     // == exp(L - max)
            acc[mt][r] = e;
            ssum += e;
        }
    }
    ssum += __shfl_xor(ssum, 16, 64);
    ssum += __shfl_xor(ssum, 32, 64);
    if (g == 0) wsum[wv][nl] = ssum;
    __syncthreads();
    float tot = (wsum[0][nl] + wsum[1][nl]) + (wsum[2][nl] + wsum[3][nl]);
    float rs = (node < n) ? (1.0f / tot) : 0.f;
    float sc = 256.f * rs;
    unsigned char* frow = &f8[nl * F8ROW];
#pragma unroll
    for (int mt = 0; mt < 8; ++mt) {
#pragma unroll
        for (int r = 0; r < 4; ++r) {
            int cl = kb + mt * 16 + g * 4 + r;
            S_T[(size_t)cl * NPAD + node] = f2bf(acc[mt][r] * rs);
        }
#ifdef HAS_FP8_CVT
        int pk = __builtin_amdgcn_cvt_pk_fp8_f32(acc[mt][0] * sc, acc[mt][1] * sc, 0, false);
        pk     = __builtin_amdgcn_cvt_pk_fp8_f32(acc[mt][2] * sc, acc[mt][3] * sc, pk, true);
#else
        int pk = (int)(f32_to_fp8_slow(acc[mt][0]*sc) | (f32_to_fp8_slow(acc[mt][1]*sc) << 8) |
                       (f32_to_fp8_slow(acc[mt][2]*sc) << 16) | (f32_to_fp8_slow(acc[mt][3]*sc) << 24));
#endif
        *(unsigned*)&frow[kb + mt * 16 + g * 4] = (unsigned)pk;
    }
    {
        const unsigned short* arow = WeT + (size_t)(wv * 16 + nl) * 64;
        bf16x8 af0 = *(const bf16x8*)&arow[g * 8];
        bf16x8 af1 = *(const bf16x8*)&arow[32 + g * 8];
        f32x4 a = __builtin_amdgcn_mfma_f32_16x16x32_bf16(af0, bf0, (f32x4){0.f,0.f,0.f,0.f}, 0, 0, 0);
        a = __builtin_amdgcn_mfma_f32_16x16x32_bf16(af1, bf1, a, 0, 0, 0);
#pragma unroll
        for (int r = 0; r < 4; ++r) {
            int ch = wv * 16 + g * 4 + r;
            float z = sd * (a[r] + st * bes[ch]);
            Z_T[(size_t)ch * NPAD + node] = f2bf(z);
        }
    }
    __syncthreads();
#pragma unroll
    for (int h = 0; h < 2; ++h) {
        int idx = t + h * 256;
        int row = idx >> 5;
        int off = (idx & 31) * 16;
        uint4 vv = *(const uint4*)&f8[row * F8ROW + off];
        int grow = n0 + row;
        if (grow < n) *(uint4*)&Sf8[(size_t)grow * KPAD + off] = vv;
    }
}

// -------- G = A^T S via slotted-CSR over fp8 S, TRANSPOSED bf16 out. 512 threads (8 waves). --------
// (measured roofline ~81us; do not touch)
#define GT_ROWS 32
__global__ void __launch_bounds__(512) g_agg_t_kernel(
        const unsigned char* __restrict__ Sf8, const int* __restrict__ degc,
        const int* __restrict__ esrc, unsigned short* __restrict__ G_T, int n) {
    __shared__ unsigned short tl[GT_ROWS * 520];
    __shared__ int nextrow;
    int base = blockIdx.x * GT_ROWS;
    int ln = threadIdx.x & 63;
    int half = ln >> 5, lc = ln & 31;    // half-wave edge slot, col chunk (16 fp8 each)
    if (threadIdx.x == 0) nextrow = 0;
    __syncthreads();
    const uint4* S4 = (const uint4*)Sf8;
    const float inv = F8_INV;
    while (true) {
        int r = 0;
        if (ln == 0) r = atomicAdd(&nextrow, 1);
        r = __shfl(r, 0, 64);
        if (r >= GT_ROWS) break;
        int node = base + r;
        float a[16];
#pragma unroll
        for (int j = 0; j < 16; ++j) a[j] = 0.f;
        if (node < n) {
            int p = node << 7;
            int pend = p + degc[node];
            for (; p + 7 < pend; p += 8) {
                int s0 = esrc[p + half];
                int s1 = esrc[p + 2 + half];
                int s2 = esrc[p + 4 + half];
                int s3 = esrc[p + 6 + half];
                uint4 v0 = S4[(size_t)s0 * 32 + lc];
                uint4 v1 = S4[(size_t)s1 * 32 + lc];
                uint4 v2 = S4[(size_t)s2 * 32 + lc];
                uint4 v3 = S4[(size_t)s3 * 32 + lc];
                accf8v4(a, v0); accf8v4(a, v1); accf8v4(a, v2); accf8v4(a, v3);
            }
            for (; p + 1 < pend; p += 2) {
                int s = esrc[p + half];
                uint4 v = S4[(size_t)s * 32 + lc];
                accf8v4(a, v);
            }
            if (p < pend && half == 0) {
                int s = esrc[p];
                uint4 v = S4[(size_t)s * 32 + lc];
                accf8v4(a, v);
            }
        }
#pragma unroll
        for (int j = 0; j < 16; ++j) a[j] += __shfl_xor(a[j], 32, 64);
        uint4 o;
        if (half == 0) {       // compile-time register indices (avoid scratch)
            o.x = packbf(a[0] * inv, a[1] * inv);
            o.y = packbf(a[2] * inv, a[3] * inv);
            o.z = packbf(a[4] * inv, a[5] * inv);
            o.w = packbf(a[6] * inv, a[7] * inv);
        } else {
            o.x = packbf(a[8]  * inv, a[9]  * inv);
            o.y = packbf(a[10] * inv, a[11] * inv);
            o.z = packbf(a[12] * inv, a[13] * inv);
            o.w = packbf(a[14] * inv, a[15] * inv);
        }
        *(uint4*)&tl[r * 520 + lc * 16 + half * 8] = o;
    }
    __syncthreads();
    {
        int k = threadIdx.x;
        unsigned wb[8];
#pragma unroll
        for (int j = 0; j < 8; ++j) {
            unsigned short lo = tl[(2 * j)     * 520 + k];
            unsigned short hi = tl[(2 * j + 1) * 520 + k];
            wb[j] = ((unsigned)hi << 16) | (unsigned)lo;
        }
        unsigned wc[8];
#pragma unroll
        for (int j = 0; j < 8; ++j) {
            unsigned short lo = tl[(16 + 2 * j) * 520 + k];
            unsigned short hi = tl[(17 + 2 * j) * 520 + k];
            wc[j] = ((unsigned)hi << 16) | (unsigned)lo;
        }
        size_t ob = (size_t)k * NPAD + base;
        *(uint4*)&G_T[ob]      = make_uint4(wb[0], wb[1], wb[2], wb[3]);
        *(uint4*)&G_T[ob + 8]  = make_uint4(wb[4], wb[5], wb[6], wb[7]);
        *(uint4*)&G_T[ob + 16] = make_uint4(wc[0], wc[1], wc[2], wc[3]);
        *(uint4*)&G_T[ob + 24] = make_uint4(wc[4], wc[5], wc[6], wc[7]);
    }
}

// ---- combined MFMA TN GEMM, 128x128 tiles, BK=32 DOUBLE-BUFFERED gload_lds staging.
//      LDS = 2 x (8+8) KB = 32 KB -> 5 blocks/CU (was 2 at BK=64): cross-block overlap
//      covers stage latency. 2-bit XOR chunk swizzle (both sides, rule #21);
//      residual 4-way ds_read conflict accepted (~1.58x on a small fraction). ----
#define CPITCH 64    // bytes per LDS row (BK=32 bf16)
__device__ inline void stage_tiles(const unsigned short* Ap, const unsigned short* Bp,
                                   int a0, int b0, int nb,
                                   unsigned short* Albuf, unsigned short* Blbuf,
                                   int wv, int srow, int schunk) {
#pragma unroll
    for (int j = 0; j < 2; ++j) {
        int rbase = j * 64 + wv * 16;          // 2 rounds x 4 waves x 16 rows = 128
        int row = rbase + srow;
        const char* gA = (const char*)(Ap + (size_t)(a0 + row) * NPAD + nb) + schunk;
        const char* gB = (const char*)(Bp + (size_t)(b0 + row) * NPAD + nb) + schunk;
        gload_lds16(gA, (char*)Albuf + rbase * CPITCH);
        gload_lds16(gB, (char*)Blbuf + rbase * CPITCH);
    }
}

__global__ void __launch_bounds__(256) mfma_comb_kernel(
        const unsigned short* __restrict__ S_T, const unsigned short* __restrict__ G_T,
        const unsigned short* __restrict__ Z_T,
        float* __restrict__ partialA, float* __restrict__ partialX, int nPer) {
    __shared__ unsigned short Al[2][128 * 32];   // 2 x 8 KB
    __shared__ unsigned short Bl[2][128 * 32];   // 2 x 8 KB
    // grid = 920 = 8 XCDs * 115 slots = 46 z * 20 tiles; dispatch round-robin -> xcd = bid%8
    const int bid = blockIdx.x;
    const int kws = (bid & 7) * 115 + (bid >> 3);   // contiguous work range per XCD
    const int tile = kws % 20;
    const int zz   = kws / 20;
    const int t = threadIdx.x;
    const int ln = t & 63, wv = t >> 6;
    const int wa = (wv & 1) * 64, wb = (wv >> 1) * 64;
    const int lm = ln & 15;
    const int lkc = (ln >> 4) << 4;                 // byte chunk of K-fragment: 0/16/32/48
    const int nbeg = zz * nPer;
    const int nend = min(nbeg + nPer, NPAD);
    const bool isA = (tile < 16);
    const unsigned short* Ap = isA ? G_T : S_T;
    const unsigned short* Bp = isA ? S_T : Z_T;
    const int a0 = isA ? (tile >> 2) * 128 : (tile - 16) * 128;
    const int b0 = isA ? (tile & 3) * 128 : 0;
    float* op = isA ? (partialA + (size_t)zz * 512 * 512)
                    : (partialX + (size_t)zz * 512 * 128);
    const int ostride = isA ? 512 : 128;
    const int srow = ln >> 2;                               // 0..15
    const int schunk = (((ln & 3) ^ (srow & 3)) << 4);      // swizzled 16B chunk in 64B row
    f32x4 acc[4][4];
#pragma unroll
    for (int i = 0; i < 4; ++i)
#pragma unroll
        for (int j = 0; j < 4; ++j) acc[i][j] = (f32x4){0.f, 0.f, 0.f, 0.f};
    // prologue: stage first K-tile into buf 0
    stage_tiles(Ap, Bp, a0, b0, nbeg, Al[0], Bl[0], wv, srow, schunk);
    __syncthreads();
    int cur = 0;
    for (int nb = nbeg; nb < nend; nb += 32) {
        int nxt = nb + 32;
        if (nxt < nend)
            stage_tiles(Ap, Bp, a0, b0, nxt, Al[cur ^ 1], Bl[cur ^ 1], wv, srow, schunk);
        const unsigned short* Ac = Al[cur];
        const unsigned short* Bc = Bl[cur];
        bf16x8 af[4], bfr[4];
#pragma unroll
        for (int i = 0; i < 4; ++i) {
            int rowA = wa + i * 16 + lm;
            af[i] = *(const bf16x8*)((const char*)Ac + rowA * CPITCH
                    + (lkc ^ ((rowA & 3) << 4)));
        }
#pragma unroll
        for (int j = 0; j < 4; ++j) {
            int rowB = wb + j * 16 + lm;
            bfr[j] = *(const bf16x8*)((const char*)Bc + rowB * CPITCH
                     + (lkc ^ ((rowB & 3) << 4)));
        }
#pragma unroll
        for (int i = 0; i < 4; ++i)
#pragma unroll
            for (int j = 0; j < 4; ++j)
                acc[i][j] = __builtin_amdgcn_mfma_f32_16x16x32_bf16(af[i], bfr[j], acc[i][j], 0, 0, 0);
        __syncthreads();   // drains vmcnt(0): next buf staged; also fences buf reuse
        cur ^= 1;
    }
#pragma unroll
    for (int i = 0; i < 4; ++i) {
#pragma unroll
        for (int j = 0; j < 4; ++j) {
            int bg = b0 + wb + j * 16 + lm;
#pragma unroll
            for (int r = 0; r < 4; ++r) {
                int ag = a0 + wa + i * 16 + (ln >> 4) * 4 + r;
                op[(size_t)ag * ostride + bg] = acc[i][j][r];
            }
        }
    }
}

// ---------------- combined split-K reduce (outX then outA) ----------------
__global__ void reduce2_kernel(const float* __restrict__ partialX, const float* __restrict__ partialA,
                               float* __restrict__ outX, float* __restrict__ outA, int Z) {
    int idx = blockIdx.x * blockDim.x + threadIdx.x;
    const int NX = KK * 64;          // 32000
    if (idx < NX) {
        int a = idx >> 6, b = idx & 63;
        const float* p = partialX + (size_t)a * 128 + b;
        float s = 0.f;
        for (int z = 0; z < Z; ++z) s += p[(size_t)z * 512 * 128];
        outX[idx] = s;
        return;
    }
    int j = idx - NX;
    if (j >= KK * KK) return;        // 250000
    int a = j / KK, b = j - a * KK;
    const float* p = partialA + (size_t)a * 512 + b;
    float s = 0.f;
    for (int z = 0; z < Z; ++z) s += p[(size_t)z * 512 * 512];
    outA[j] = s;
}

extern "C" void kernel_launch(void* const* d_in, const int* in_sizes, int n_in,
                              void* d_out, int out_size, void* d_ws, size_t ws_size,
                              hipStream_t stream) {
    const float* x        = (const float*)d_in[0];
    const int*   ei       = (const int*)d_in[1];
    const float* W_embed  = (const float*)d_in[2];
    const float* b_embed  = (const float*)d_in[3];
    const float* W_assign = (const float*)d_in[4];
    const float* b_assign = (const float*)d_in[5];

    const int N = in_sizes[0] / DD;     // 50000
    const int E = in_sizes[1] / 2;      // 800000
    const int C = in_sizes[3];          // 64
    const int K = in_sizes[5];          // 500

    const int* rowv = ei;
    const int* colv = ei + E;

    char* p = (char*)d_ws;
    auto alloc = [&](size_t bytes) -> void* {
        void* r = (void*)p;
        p += (bytes + 255) & ~(size_t)255;
        return r;
    };
    int*   bcur     = (int*)alloc((size_t)2 * NBUCK * 4);
    int*   bcurC    = bcur;
    int*   bcurR    = bcur + NBUCK;
    int*   bstoreC  = (int*)alloc((size_t)NBUCK * BCAP * 4);               // 4.8 MB
    unsigned char* bstoreR = (unsigned char*)alloc((size_t)NBUCK * BCAP);  // 1.2 MB
    int*   degc     = (int*)alloc((size_t)N * 4);
    float* dinv     = (float*)alloc((size_t)N * 4);
    float* tsum     = (float*)alloc((size_t)N * 4);
    int*   esrc     = (int*)alloc((size_t)NPAD * SLOTS * 4);               // 25.6 MB slotted CSR
    float* u        = (float*)alloc((size_t)N * DD * 4);                   // 12.8 MB (partialX)
    unsigned short* xb   = (unsigned short*)alloc((size_t)N * DD * 2);
    unsigned short* ubuf = (unsigned short*)alloc((size_t)NPAD * DD * 2);
    unsigned short* WaT  = (unsigned short*)alloc((size_t)KPAD * DD * 2);
    unsigned short* WeT  = (unsigned short*)alloc((size_t)DD * DD * 2);
    unsigned char*  Sf8  = (unsigned char*)alloc((size_t)N * KPAD);
    unsigned short* S_T  = (unsigned short*)alloc((size_t)KPAD * NPAD * 2);
    unsigned short* G_T  = (unsigned short*)alloc((size_t)KPAD * NPAD * 2);
    unsigned short* Z_T  = (unsigned short*)alloc((size_t)128 * NPAD * 2);

    // split-K (nPer=1088, Z=46: 1088*46 == NPAD)
    const int nPer = 1088, ZSK = 46;
    float* partialA = (float*)alloc((size_t)ZSK * 512 * 512 * 4);          // 48.2 MB
    float* partialX = (float*)u;    // 46*512*128*4 = 12.06 MB <= 12.8 MB

    float* outX = (float*)d_out;            // [500][64]
    float* outA = outX + (size_t)K * C;     // [500][500]

    (void)hipMemsetAsync(bcur, 0, (size_t)2 * NBUCK * 4, stream);

    // two-phase binned CSR build
    binA_kernel<<<(E + 1023) / 1024, 256, 0, stream>>>(rowv, colv, bcurC, bcurR,
                                                       bstoreC, bstoreR, E);
    buildcsr_kernel<<<NBUCK, 256, 0, stream>>>(bcurC, bstoreC, esrc, degc, N);
    rowdeg_kernel<<<NBUCK, 256, 0, stream>>>(bcurR, bstoreR, dinv, N);

    // fused prep: xb + WaT + WeT
    {
        int total = N * 16 + (KPAD + DD) * 64;
        prep_kernel<<<(total + 255) / 256, 256, 0, stream>>>(x, dinv, xb, W_assign, W_embed,
                                                             WaT, WeT, N * 16);
    }

    agg_kernel<<<NPAD / 4, 256, 0, stream>>>(xb, dinv, degc, esrc, tsum, ubuf, N);

    fused_s3_kernel<<<NPAD / 16, 256, 0, stream>>>(ubuf, WaT, WeT, b_assign, b_embed,
                                                   dinv, tsum, S_T, Sf8, Z_T, N);

    g_agg_t_kernel<<<NPAD / GT_ROWS, 512, 0, stream>>>(Sf8, degc, esrc, G_T, N);

    // combined GEMM: next_A (tiles 0..15) + next_X (tiles 16..19), z-grouped XCD swizzle
    mfma_comb_kernel<<<20 * ZSK, 256, 0, stream>>>(S_T, G_T, Z_T, partialA, partialX, nPer);

    // combined reduce
    {
        int total = K * C + K * K;   // 282000
        reduce2_kernel<<<(total + 255) / 256, 256, 0, stream>>>(partialX, partialA, outX, outA, ZSK);
    }
}

// Round 17
// 321.308 us; speedup vs baseline: 1.0604x; 1.0604x over previous
//
#include <hip/hip_runtime.h>
#include <hip/hip_bf16.h>
#include <math.h>

// Problem constants: N=50000, E=800000, D=64, K=500, C=64
#define DD 64
#define KK 500
#define KPAD 512
#define NPAD 50048   // N padded to multiple of 64
#define NS 50176     // N padded to multiple of 256 buckets (196*256)
#define SLOTS 128    // slotted-CSR capacity per node
#define NBUCK 196    // node buckets of 256 nodes each (196*256 = 50176)
#define BCAP 6144    // per-bucket edge capacity (mean 4096, sigma 64 -> +32 sigma)

typedef __attribute__((ext_vector_type(8))) short bf16x8;
typedef __attribute__((ext_vector_type(4))) float f32x4;

#if defined(__has_builtin)
#if __has_builtin(__builtin_amdgcn_cvt_pk_f32_fp8) && __has_builtin(__builtin_amdgcn_cvt_pk_fp8_f32)
#define HAS_FP8_CVT 1
#endif
#if __has_builtin(__builtin_amdgcn_exp2f)
#define EXP2(x) __builtin_amdgcn_exp2f(x)
#endif
#endif
#ifndef EXP2
#define EXP2(x) exp2f(x)
#endif

// final scale for fp8 accumulation (decode scale deferred in the no-builtin path)
#ifdef HAS_FP8_CVT
#define F8_INV (1.0f / 256.f)
#else
#define F8_INV 0x1p112f
#endif

__device__ inline unsigned short f2bf(float f) {
    unsigned u = __float_as_uint(f);
    u += 0x7fffu + ((u >> 16) & 1u);          // RNE
    return (unsigned short)(u >> 16);
}
__device__ inline unsigned packbf(float lo, float hi) {
    return ((unsigned)f2bf(hi) << 16) | (unsigned)f2bf(lo);
}
__device__ inline float bf2f(unsigned short h) {
    return __uint_as_float((unsigned)h << 16);
}

// async global->LDS, 16B per lane; LDS dest = uniform base + lane*16
__device__ inline void gload_lds16(const void* g, void* l) {
    __builtin_amdgcn_global_load_lds(
        (const __attribute__((address_space(1))) unsigned int*)g,
        (__attribute__((address_space(3))) unsigned int*)l, 16, 0, 0);
}

#ifndef HAS_FP8_CVT
// fp8 e4m3 bits -> f32 scaled by 2^-120 (exponent rebias via bit placement; exact incl. subnormals)
__device__ inline float f8bits(unsigned b) {
    return __uint_as_float(((b & 0x80u) << 24) | ((b & 0x7fu) << 20));
}
__device__ inline unsigned f32_to_fp8_slow(float f) {
    unsigned sgn = (__float_as_uint(f) >> 24) & 0x80u;
    float af = fabsf(f);
    if (!(af > 0.f)) return sgn;
    if (af >= 448.f) return sgn | 0x7E;
    int e; frexpf(af, &e);
    int E = e - 1 + 7;
    if (E < 1) { unsigned q = (unsigned)rintf(ldexpf(af, 9)); return sgn | q; }
    unsigned q = (unsigned)rintf(ldexpf(af, 10 - E));
    if (q >= 16) { q = 8; E++; }
    if (E > 15 || (E == 15 && q - 8 >= 7)) return sgn | 0x7E;
    return sgn | ((unsigned)E << 3) | (q - 8);
}
#endif

// 16 fp8 values (uint4) -> a[0..15]
__device__ inline void accf8v4(float* a, uint4 v) {
#ifdef HAS_FP8_CVT
    auto f0 = __builtin_amdgcn_cvt_pk_f32_fp8(v.x, false);
    a[0] += f0[0]; a[1] += f0[1];
    auto f1 = __builtin_amdgcn_cvt_pk_f32_fp8(v.x, true);
    a[2] += f1[0]; a[3] += f1[1];
    auto f2 = __builtin_amdgcn_cvt_pk_f32_fp8(v.y, false);
    a[4] += f2[0]; a[5] += f2[1];
    auto f3 = __builtin_amdgcn_cvt_pk_f32_fp8(v.y, true);
    a[6] += f3[0]; a[7] += f3[1];
    auto f4 = __builtin_amdgcn_cvt_pk_f32_fp8(v.z, false);
    a[8] += f4[0]; a[9] += f4[1];
    auto f5 = __builtin_amdgcn_cvt_pk_f32_fp8(v.z, true);
    a[10] += f5[0]; a[11] += f5[1];
    auto f6 = __builtin_amdgcn_cvt_pk_f32_fp8(v.w, false);
    a[12] += f6[0]; a[13] += f6[1];
    auto f7 = __builtin_amdgcn_cvt_pk_f32_fp8(v.w, true);
    a[14] += f7[0]; a[15] += f7[1];
#else
    a[0]  += f8bits(v.x & 0xff);         a[1]  += f8bits((v.x >> 8) & 0xff);
    a[2]  += f8bits((v.x >> 16) & 0xff); a[3]  += f8bits((v.x >> 24) & 0xff);
    a[4]  += f8bits(v.y & 0xff);         a[5]  += f8bits((v.y >> 8) & 0xff);
    a[6]  += f8bits((v.y >> 16) & 0xff); a[7]  += f8bits((v.y >> 24) & 0xff);
    a[8]  += f8bits(v.z & 0xff);         a[9]  += f8bits((v.z >> 8) & 0xff);
    a[10] += f8bits((v.z >> 16) & 0xff); a[11] += f8bits((v.z >> 24) & 0xff);
    a[12] += f8bits(v.w & 0xff);         a[13] += f8bits((v.w >> 8) & 0xff);
    a[14] += f8bits((v.w >> 16) & 0xff); a[15] += f8bits((v.w >> 24) & 0xff);
#endif
}

// 4 bf16 values (uint2) -> a[0..3]
__device__ inline void accbf4(float* a, uint2 v) {
    a[0] += __uint_as_float(v.x << 16);
    a[1] += __uint_as_float(v.x & 0xffff0000u);
    a[2] += __uint_as_float(v.y << 16);
    a[3] += __uint_as_float(v.y & 0xffff0000u);
}

// ---------------- phase A: bin edges by col-bucket and row-bucket ----------------
__global__ void __launch_bounds__(256) binA_kernel(
        const int* __restrict__ rowv, const int* __restrict__ colv,
        int* __restrict__ bcurC, int* __restrict__ bcurR,
        int* __restrict__ bstoreC, unsigned char* __restrict__ bstoreR, int E) {
    __shared__ int hc[NBUCK], hr[NBUCK], baseC[NBUCK], baseR[NBUCK];
    int t = threadIdx.x;
    if (t < NBUCK) { hc[t] = 0; hr[t] = 0; }
    __syncthreads();
    int e0 = blockIdx.x * 1024 + t * 4;
    int r[4], c[4];
#pragma unroll
    for (int i = 0; i < 4; ++i) {
        int e = e0 + i;
        if (e < E) {
            r[i] = rowv[e];
            c[i] = colv[e];
            atomicAdd(&hc[c[i] >> 8], 1);
            atomicAdd(&hr[r[i] >> 8], 1);
        } else {
            r[i] = -1; c[i] = -1;
        }
    }
    __syncthreads();
    if (t < NBUCK) {
        baseC[t] = atomicAdd(&bcurC[t], hc[t]);
        baseR[t] = atomicAdd(&bcurR[t], hr[t]);
        hc[t] = 0; hr[t] = 0;
    }
    __syncthreads();
#pragma unroll
    for (int i = 0; i < 4; ++i) {
        if (r[i] >= 0) {
            int bc = c[i] >> 8;
            int oc = baseC[bc] + atomicAdd(&hc[bc], 1);
            if (oc < BCAP) bstoreC[bc * BCAP + oc] = (r[i] << 8) | (c[i] & 255);
            int br = r[i] >> 8;
            int orr = baseR[br] + atomicAdd(&hr[br], 1);
            if (orr < BCAP) bstoreR[br * BCAP + orr] = (unsigned char)(r[i] & 255);
        }
    }
}

// ---------------- phase B1: build slotted CSR per bucket with LDS cursors ----------------
__global__ void __launch_bounds__(256) buildcsr_kernel(
        const int* __restrict__ bcurC, const int* __restrict__ bstoreC,
        int* __restrict__ esrc, int* __restrict__ degc, int n) {
    __shared__ int cur[256];
    int b = blockIdx.x, t = threadIdx.x;
    cur[t] = 0;
    __syncthreads();
    int cnt = min(bcurC[b], BCAP);
    const int* src = bstoreC + b * BCAP;
    for (int i = t; i < cnt; i += 256) {
        int packed = src[i];
        int cl = packed & 255, rr = packed >> 8;
        int p = atomicAdd(&cur[cl], 1);
        if (p < SLOTS) esrc[((size_t)(b * 256 + cl) << 7) + p] = rr;
    }
    __syncthreads();
    int node = b * 256 + t;
    if (node < n) degc[node] = min(cur[t], SLOTS);
}

// ---------------- phase B2: row degrees -> dinv ----------------
__global__ void __launch_bounds__(256) rowdeg_kernel(
        const int* __restrict__ bcurR, const unsigned char* __restrict__ bstoreR,
        float* __restrict__ dinv, int n) {
    __shared__ int cnt[256];
    int b = blockIdx.x, t = threadIdx.x;
    cnt[t] = 0;
    __syncthreads();
    int c = min(bcurR[b], BCAP);
    const unsigned char* src = bstoreR + b * BCAP;
    for (int i = t; i < c; i += 256) {
        atomicAdd(&cnt[src[i]], 1);
    }
    __syncthreads();
    int node = b * 256 + t;
    if (node < n) dinv[node] = 1.0f / sqrtf((float)(cnt[t] + 1));
}

// ---- fused prep: xb = bf16(dinv*x) + WaT/WeT transposes ----
__global__ void prep_kernel(const float* __restrict__ x, const float* __restrict__ dinv,
                            unsigned short* __restrict__ xb,
                            const float* __restrict__ Wa, const float* __restrict__ We,
                            unsigned short* __restrict__ WaT, unsigned short* __restrict__ WeT,
                            int n16) {
    int idx = blockIdx.x * blockDim.x + threadIdx.x;
    if (idx < n16) {
        int i = idx >> 4;
        float di = dinv[i];
        float4 v = ((const float4*)x)[idx];
        uint2 o;
        o.x = packbf(di * v.x, di * v.y);
        o.y = packbf(di * v.z, di * v.w);
        ((uint2*)xb)[idx] = o;
        return;
    }
    int j = idx - n16;
    if (j < KPAD * 64) {
        int c = j >> 6, d = j & 63;
        float v = (c < KK) ? Wa[(size_t)d * KK + c] : 0.f;
        WaT[j] = f2bf(v);
    } else if (j < (KPAD + DD) * 64) {
        int k = j - KPAD * 64;
        int c = k >> 6, d = k & 63;
        WeT[k] = f2bf(We[(size_t)d * 64 + c]);
    }
}

// ---- ub = bf16(xb[i] + sum_{in} xb[s]);  t[i] = dinv[i] + sum_{in} dinv[s] ----
// 16 lanes per edge (uint2 = 4 bf16 cols each), 4 edges in flight per load instr. (R11-proven)
__global__ void agg_kernel(const unsigned short* __restrict__ xb, const float* __restrict__ dinv,
                           const int* __restrict__ degc, const int* __restrict__ esrc,
                           float* __restrict__ t, unsigned short* __restrict__ ub, int n) {
    int wv = (blockIdx.x * blockDim.x + threadIdx.x) >> 6;
    int ln = threadIdx.x & 63;
    int g = ln >> 4, q = ln & 15;      // group 0..3 (edge slot), col chunk 0..15
    if (wv >= NPAD) return;
    if (wv >= n) {
        if (g == 0) ((uint2*)ub)[(size_t)wv * 16 + q] = make_uint2(0u, 0u);
        return;
    }
    const uint2* X2 = (const uint2*)xb;
    float ac[4] = {0.f, 0.f, 0.f, 0.f};
    float ts = 0.f;
    if (g == 0) {
        uint2 v = X2[(size_t)wv * 16 + q];   // self term, counted once
        accbf4(ac, v);
    }
    int p = wv << 7;
    int pend = p + degc[wv];
    for (; p + 7 < pend; p += 8) {
        int s0 = esrc[p + g];
        int s1 = esrc[p + 4 + g];
        uint2 v0 = X2[(size_t)s0 * 16 + q];
        uint2 v1 = X2[(size_t)s1 * 16 + q];
        float w0 = dinv[s0], w1 = dinv[s1];
        accbf4(ac, v0); accbf4(ac, v1);
        ts += w0 + w1;
    }
    for (; p + 3 < pend; p += 4) {
        int s = esrc[p + g];
        uint2 v = X2[(size_t)s * 16 + q];
        ts += dinv[s];
        accbf4(ac, v);
    }
    if (g < pend - p) {
        int s = esrc[p + g];
        uint2 v = X2[(size_t)s * 16 + q];
        ts += dinv[s];
        accbf4(ac, v);
    }
#pragma unroll
    for (int j = 0; j < 4; ++j) {
        ac[j] += __shfl_xor(ac[j], 16, 64);
        ac[j] += __shfl_xor(ac[j], 32, 64);
    }
    ts += __shfl_xor(ts, 16, 64);
    ts += __shfl_xor(ts, 32, 64);
    if (g == 0) {
        uint2 o;
        o.x = packbf(ac[0], ac[1]);
        o.y = packbf(ac[2], ac[3]);
        ((uint2*)ub)[(size_t)wv * 16 + q] = o;
        if (q == 0) t[wv] = dinv[wv] + ts;
    }
}

// ---- fused assign (MFMA, high-occupancy): block = 16 nodes, 4 waves split 512 clusters.
//      Softmax in exp2 domain (R15-proven: one v_exp_f32 per element). ----
#define F8ROW 520
#define LOG2E 1.44269504f
__global__ void __launch_bounds__(256) fused_s3_kernel(
        const unsigned short* __restrict__ ub, const unsigned short* __restrict__ WaT,
        const unsigned short* __restrict__ WeT,
        const float* __restrict__ ba, const float* __restrict__ be,
        const float* __restrict__ dinv, const float* __restrict__ tsum,
        unsigned short* __restrict__ S_T, unsigned char* __restrict__ Sf8,
        unsigned short* __restrict__ Z_T, int n) {
    __shared__ float bs[512];
    __shared__ float bes[64];
    __shared__ float wmax[4][16];
    __shared__ float wsum[4][16];
    __shared__ unsigned char f8[16 * F8ROW];
    int t = threadIdx.x;
    int n0 = blockIdx.x * 16;
    {
        float b0 = (t * 2     < KK) ? ba[t * 2]     : 0.f;
        float b1 = (t * 2 + 1 < KK) ? ba[t * 2 + 1] : 0.f;
        bs[t * 2] = b0; bs[t * 2 + 1] = b1;
        if (t < 64) bes[t] = be[t];
    }
    __syncthreads();
    int wv = t >> 6, ln = t & 63;
    int nl = ln & 15;
    int g  = ln >> 4;
    int node = n0 + nl;
    int kb = wv * 128;
    float sd = (node < n) ? dinv[node] : 0.f;
    float st = (node < n) ? tsum[node] : 0.f;
    const unsigned short* brow = ub + (size_t)node * 64;
    bf16x8 bf0 = *(const bf16x8*)&brow[g * 8];
    bf16x8 bf1 = *(const bf16x8*)&brow[32 + g * 8];
    f32x4 acc[8];
#pragma unroll
    for (int mt = 0; mt < 8; ++mt) {
        const unsigned short* arow = WaT + (size_t)(kb + mt * 16 + nl) * 64;
        bf16x8 af0 = *(const bf16x8*)&arow[g * 8];
        bf16x8 af1 = *(const bf16x8*)&arow[32 + g * 8];
        f32x4 a = __builtin_amdgcn_mfma_f32_16x16x32_bf16(af0, bf0, (f32x4){0.f,0.f,0.f,0.f}, 0, 0, 0);
        acc[mt] = __builtin_amdgcn_mfma_f32_16x16x32_bf16(af1, bf1, a, 0, 0, 0);
    }
    float sdl = sd * LOG2E;
    float m = -1e30f;
#pragma unroll
    for (int mt = 0; mt < 8; ++mt) {
#pragma unroll
        for (int r = 0; r < 4; ++r) {
            int cl = kb + mt * 16 + g * 4 + r;
            float L = sdl * (acc[mt][r] + st * bs[cl]);   // logit * log2(e)
            if (cl >= KK) L = -1e30f;
            acc[mt][r] = L;
            m = fmaxf(m, L);
        }
    }
    m = fmaxf(m, __shfl_xor(m, 16, 64));
    m = fmaxf(m, __shfl_xor(m, 32, 64));
    if (g == 0) wmax[wv][nl] = m;
    __syncthreads();
    m = fmaxf(fmaxf(wmax[0][nl], wmax[1][nl]), fmaxf(wmax[2][nl], wmax[3][nl]));
    float ssum = 0.f;
#pragma unroll
    for (int mt = 0; mt < 8; ++mt) {
#pragma unroll
        for (int r = 0; r < 4; ++r) {
            float e = EXP2(acc[mt][r] - m);     // == exp(L - max)
            acc[mt][r] = e;
            ssum += e;
        }
    }
    ssum += __shfl_xor(ssum, 16, 64);
    ssum += __shfl_xor(ssum, 32, 64);
    if (g == 0) wsum[wv][nl] = ssum;
    __syncthreads();
    float tot = (wsum[0][nl] + wsum[1][nl]) + (wsum[2][nl] + wsum[3][nl]);
    float rs = (node < n) ? (1.0f / tot) : 0.f;
    float sc = 256.f * rs;
    unsigned char* frow = &f8[nl * F8ROW];
#pragma unroll
    for (int mt = 0; mt < 8; ++mt) {
#pragma unroll
        for (int r = 0; r < 4; ++r) {
            int cl = kb + mt * 16 + g * 4 + r;
            S_T[(size_t)cl * NPAD + node] = f2bf(acc[mt][r] * rs);
        }
#ifdef HAS_FP8_CVT
        int pk = __builtin_amdgcn_cvt_pk_fp8_f32(acc[mt][0] * sc, acc[mt][1] * sc, 0, false);
        pk     = __builtin_amdgcn_cvt_pk_fp8_f32(acc[mt][2] * sc, acc[mt][3] * sc, pk, true);
#else
        int pk = (int)(f32_to_fp8_slow(acc[mt][0]*sc) | (f32_to_fp8_slow(acc[mt][1]*sc) << 8) |
                       (f32_to_fp8_slow(acc[mt][2]*sc) << 16) | (f32_to_fp8_slow(acc[mt][3]*sc) << 24));
#endif
        *(unsigned*)&frow[kb + mt * 16 + g * 4] = (unsigned)pk;
    }
    {
        const unsigned short* arow = WeT + (size_t)(wv * 16 + nl) * 64;
        bf16x8 af0 = *(const bf16x8*)&arow[g * 8];
        bf16x8 af1 = *(const bf16x8*)&arow[32 + g * 8];
        f32x4 a = __builtin_amdgcn_mfma_f32_16x16x32_bf16(af0, bf0, (f32x4){0.f,0.f,0.f,0.f}, 0, 0, 0);
        a = __builtin_amdgcn_mfma_f32_16x16x32_bf16(af1, bf1, a, 0, 0, 0);
#pragma unroll
        for (int r = 0; r < 4; ++r) {
            int ch = wv * 16 + g * 4 + r;
            float z = sd * (a[r] + st * bes[ch]);
            Z_T[(size_t)ch * NPAD + node] = f2bf(z);
        }
    }
    __syncthreads();
#pragma unroll
    for (int h = 0; h < 2; ++h) {
        int idx = t + h * 256;
        int row = idx >> 5;
        int off = (idx & 31) * 16;
        uint4 vv = *(const uint4*)&f8[row * F8ROW + off];
        int grow = n0 + row;
        if (grow < n) *(uint4*)&Sf8[(size_t)grow * KPAD + off] = vv;
    }
}

// -------- G = A^T S via slotted-CSR over fp8 S, TRANSPOSED bf16 out. 512 threads (8 waves). --------
// (measured roofline ~81us; do not touch)
#define GT_ROWS 32
__global__ void __launch_bounds__(512) g_agg_t_kernel(
        const unsigned char* __restrict__ Sf8, const int* __restrict__ degc,
        const int* __restrict__ esrc, unsigned short* __restrict__ G_T, int n) {
    __shared__ unsigned short tl[GT_ROWS * 520];
    __shared__ int nextrow;
    int base = blockIdx.x * GT_ROWS;
    int ln = threadIdx.x & 63;
    int half = ln >> 5, lc = ln & 31;    // half-wave edge slot, col chunk (16 fp8 each)
    if (threadIdx.x == 0) nextrow = 0;
    __syncthreads();
    const uint4* S4 = (const uint4*)Sf8;
    const float inv = F8_INV;
    while (true) {
        int r = 0;
        if (ln == 0) r = atomicAdd(&nextrow, 1);
        r = __shfl(r, 0, 64);
        if (r >= GT_ROWS) break;
        int node = base + r;
        float a[16];
#pragma unroll
        for (int j = 0; j < 16; ++j) a[j] = 0.f;
        if (node < n) {
            int p = node << 7;
            int pend = p + degc[node];
            for (; p + 7 < pend; p += 8) {
                int s0 = esrc[p + half];
                int s1 = esrc[p + 2 + half];
                int s2 = esrc[p + 4 + half];
                int s3 = esrc[p + 6 + half];
                uint4 v0 = S4[(size_t)s0 * 32 + lc];
                uint4 v1 = S4[(size_t)s1 * 32 + lc];
                uint4 v2 = S4[(size_t)s2 * 32 + lc];
                uint4 v3 = S4[(size_t)s3 * 32 + lc];
                accf8v4(a, v0); accf8v4(a, v1); accf8v4(a, v2); accf8v4(a, v3);
            }
            for (; p + 1 < pend; p += 2) {
                int s = esrc[p + half];
                uint4 v = S4[(size_t)s * 32 + lc];
                accf8v4(a, v);
            }
            if (p < pend && half == 0) {
                int s = esrc[p];
                uint4 v = S4[(size_t)s * 32 + lc];
                accf8v4(a, v);
            }
        }
#pragma unroll
        for (int j = 0; j < 16; ++j) a[j] += __shfl_xor(a[j], 32, 64);
        uint4 o;
        if (half == 0) {       // compile-time register indices (avoid scratch)
            o.x = packbf(a[0] * inv, a[1] * inv);
            o.y = packbf(a[2] * inv, a[3] * inv);
            o.z = packbf(a[4] * inv, a[5] * inv);
            o.w = packbf(a[6] * inv, a[7] * inv);
        } else {
            o.x = packbf(a[8]  * inv, a[9]  * inv);
            o.y = packbf(a[10] * inv, a[11] * inv);
            o.z = packbf(a[12] * inv, a[13] * inv);
            o.w = packbf(a[14] * inv, a[15] * inv);
        }
        *(uint4*)&tl[r * 520 + lc * 16 + half * 8] = o;
    }
    __syncthreads();
    {
        int k = threadIdx.x;
        unsigned wb[8];
#pragma unroll
        for (int j = 0; j < 8; ++j) {
            unsigned short lo = tl[(2 * j)     * 520 + k];
            unsigned short hi = tl[(2 * j + 1) * 520 + k];
            wb[j] = ((unsigned)hi << 16) | (unsigned)lo;
        }
        unsigned wc[8];
#pragma unroll
        for (int j = 0; j < 8; ++j) {
            unsigned short lo = tl[(16 + 2 * j) * 520 + k];
            unsigned short hi = tl[(17 + 2 * j) * 520 + k];
            wc[j] = ((unsigned)hi << 16) | (unsigned)lo;
        }
        size_t ob = (size_t)k * NPAD + base;
        *(uint4*)&G_T[ob]      = make_uint4(wb[0], wb[1], wb[2], wb[3]);
        *(uint4*)&G_T[ob + 8]  = make_uint4(wb[4], wb[5], wb[6], wb[7]);
        *(uint4*)&G_T[ob + 16] = make_uint4(wc[0], wc[1], wc[2], wc[3]);
        *(uint4*)&G_T[ob + 24] = make_uint4(wc[4], wc[5], wc[6], wc[7]);
    }
}

// ---- combined MFMA TN GEMM, uniform 128x128 tiles, BK=64 DOUBLE-BUFFERED gload_lds
//      staging (R15-measured baseline). ZSK=24 split-K (halved partial traffic).
//      z-grouped XCD swizzle + XOR-16B-chunk swizzle (both sides, rule #21). ----
#define ZSK 24
#define NPER 2112    // 33*64; 24*2112 = 50688 >= NPAD
#define CPITCH 128   // bytes per LDS row (BK=64 bf16, no pad; swizzle kills conflicts)
__device__ inline void stage_tiles(const unsigned short* Ap, const unsigned short* Bp,
                                   int a0, int b0, int nb,
                                   unsigned short* Albuf, unsigned short* Blbuf,
                                   int wv, int srow, int schunk) {
#pragma unroll
    for (int j = 0; j < 4; ++j) {
        int rbase = (j * 4 + wv) * 8;
        int row = rbase + srow;
        const char* gA = (const char*)(Ap + (size_t)(a0 + row) * NPAD + nb) + schunk;
        const char* gB = (const char*)(Bp + (size_t)(b0 + row) * NPAD + nb) + schunk;
        gload_lds16(gA, (char*)Albuf + rbase * CPITCH);
        gload_lds16(gB, (char*)Blbuf + rbase * CPITCH);
    }
}

__global__ void __launch_bounds__(256) mfma_comb_kernel(
        const unsigned short* __restrict__ S_T, const unsigned short* __restrict__ G_T,
        const unsigned short* __restrict__ Z_T,
        float* __restrict__ partialA, float* __restrict__ partialX) {
    __shared__ unsigned short Al[2][128 * 64];   // 2 x 16 KB
    __shared__ unsigned short Bl[2][128 * 64];   // 2 x 16 KB
    // grid = 480 = 8 XCDs * 60 slots = 24 z * 20 tiles; dispatch round-robin -> xcd = bid%8
    const int bid = blockIdx.x;
    const int kws = (bid & 7) * 60 + (bid >> 3);   // contiguous work range per XCD
    const int tile = kws % 20;
    const int zz   = kws / 20;
    const int t = threadIdx.x;
    const int ln = t & 63, wv = t >> 6;
    const int wa = (wv & 1) * 64, wb = (wv >> 1) * 64;
    const int lm = ln & 15, lk = (ln >> 4) * 8;
    const int nbeg = zz * NPER;
    const int nend = min(nbeg + NPER, NPAD);
    const bool isA = (tile < 16);
    const unsigned short* Ap = isA ? G_T : S_T;
    const unsigned short* Bp = isA ? S_T : Z_T;
    const int a0 = isA ? (tile >> 2) * 128 : (tile - 16) * 128;
    const int b0 = isA ? (tile & 3) * 128 : 0;
    float* op = isA ? (partialA + (size_t)zz * 512 * 512)
                    : (partialX + (size_t)zz * 512 * 128);
    const int ostride = isA ? 512 : 128;
    const int srow = ln >> 3;                              // 0..7
    const int schunk = ((ln & 7) * 16) ^ (srow << 4);      // swizzled 16B chunk in 128B row
    f32x4 acc[4][4];
#pragma unroll
    for (int i = 0; i < 4; ++i)
#pragma unroll
        for (int j = 0; j < 4; ++j) acc[i][j] = (f32x4){0.f, 0.f, 0.f, 0.f};
    // prologue: stage first tile into buf 0
    stage_tiles(Ap, Bp, a0, b0, nbeg, Al[0], Bl[0], wv, srow, schunk);
    __syncthreads();
    int cur = 0;
    for (int nb = nbeg; nb < nend; nb += 64) {
        int nxt = nb + 64;
        if (nxt < nend)
            stage_tiles(Ap, Bp, a0, b0, nxt, Al[cur ^ 1], Bl[cur ^ 1], wv, srow, schunk);
        const unsigned short* Ac = Al[cur];
        const unsigned short* Bc = Bl[cur];
#pragma unroll
        for (int ks = 0; ks < 64; ks += 32) {
            bf16x8 af[4], bfr[4];
#pragma unroll
            for (int i = 0; i < 4; ++i) {
                int rowA = wa + i * 16 + lm;
                af[i] = *(const bf16x8*)((const char*)Ac + rowA * CPITCH
                        + (((ks + lk) * 2) ^ ((rowA & 7) << 4)));
            }
#pragma unroll
            for (int j = 0; j < 4; ++j) {
                int rowB = wb + j * 16 + lm;
                bfr[j] = *(const bf16x8*)((const char*)Bc + rowB * CPITCH
                         + (((ks + lk) * 2) ^ ((rowB & 7) << 4)));
            }
#pragma unroll
            for (int i = 0; i < 4; ++i)
#pragma unroll
                for (int j = 0; j < 4; ++j)
                    acc[i][j] = __builtin_amdgcn_mfma_f32_16x16x32_bf16(af[i], bfr[j], acc[i][j], 0, 0, 0);
        }
        __syncthreads();   // drains vmcnt(0): next buf staged; also fences buf reuse
        cur ^= 1;
    }
#pragma unroll
    for (int i = 0; i < 4; ++i) {
#pragma unroll
        for (int j = 0; j < 4; ++j) {
            int bg = b0 + wb + j * 16 + lm;
#pragma unroll
            for (int r = 0; r < 4; ++r) {
                int ag = a0 + wa + i * 16 + (ln >> 4) * 4 + r;
                op[(size_t)ag * ostride + bg] = acc[i][j][r];
            }
        }
    }
}

// ---------------- combined split-K reduce (outX then outA) ----------------
__global__ void reduce2_kernel(const float* __restrict__ partialX, const float* __restrict__ partialA,
                               float* __restrict__ outX, float* __restrict__ outA, int Z) {
    int idx = blockIdx.x * blockDim.x + threadIdx.x;
    const int NX = KK * 64;          // 32000
    if (idx < NX) {
        int a = idx >> 6, b = idx & 63;
        const float* p = partialX + (size_t)a * 128 + b;
        float s = 0.f;
        for (int z = 0; z < Z; ++z) s += p[(size_t)z * 512 * 128];
        outX[idx] = s;
        return;
    }
    int j = idx - NX;
    if (j >= KK * KK) return;        // 250000
    int a = j / KK, b = j - a * KK;
    const float* p = partialA + (size_t)a * 512 + b;
    float s = 0.f;
    for (int z = 0; z < Z; ++z) s += p[(size_t)z * 512 * 512];
    outA[j] = s;
}

extern "C" void kernel_launch(void* const* d_in, const int* in_sizes, int n_in,
                              void* d_out, int out_size, void* d_ws, size_t ws_size,
                              hipStream_t stream) {
    const float* x        = (const float*)d_in[0];
    const int*   ei       = (const int*)d_in[1];
    const float* W_embed  = (const float*)d_in[2];
    const float* b_embed  = (const float*)d_in[3];
    const float* W_assign = (const float*)d_in[4];
    const float* b_assign = (const float*)d_in[5];

    const int N = in_sizes[0] / DD;     // 50000
    const int E = in_sizes[1] / 2;      // 800000
    const int C = in_sizes[3];          // 64
    const int K = in_sizes[5];          // 500

    const int* rowv = ei;
    const int* colv = ei + E;

    char* p = (char*)d_ws;
    auto alloc = [&](size_t bytes) -> void* {
        void* r = (void*)p;
        p += (bytes + 255) & ~(size_t)255;
        return r;
    };
    int*   bcur     = (int*)alloc((size_t)2 * NBUCK * 4);
    int*   bcurC    = bcur;
    int*   bcurR    = bcur + NBUCK;
    int*   bstoreC  = (int*)alloc((size_t)NBUCK * BCAP * 4);               // 4.8 MB
    unsigned char* bstoreR = (unsigned char*)alloc((size_t)NBUCK * BCAP);  // 1.2 MB
    int*   degc     = (int*)alloc((size_t)N * 4);
    float* dinv     = (float*)alloc((size_t)N * 4);
    float* tsum     = (float*)alloc((size_t)N * 4);
    int*   esrc     = (int*)alloc((size_t)NPAD * SLOTS * 4);               // 25.6 MB slotted CSR
    float* u        = (float*)alloc((size_t)N * DD * 4);                   // 12.8 MB (partialX)
    unsigned short* xb   = (unsigned short*)alloc((size_t)N * DD * 2);
    unsigned short* ubuf = (unsigned short*)alloc((size_t)NPAD * DD * 2);
    unsigned short* WaT  = (unsigned short*)alloc((size_t)KPAD * DD * 2);
    unsigned short* WeT  = (unsigned short*)alloc((size_t)DD * DD * 2);
    unsigned char*  Sf8  = (unsigned char*)alloc((size_t)N * KPAD);
    unsigned short* S_T  = (unsigned short*)alloc((size_t)KPAD * NPAD * 2);
    unsigned short* G_T  = (unsigned short*)alloc((size_t)KPAD * NPAD * 2);
    unsigned short* Z_T  = (unsigned short*)alloc((size_t)128 * NPAD * 2);

    // split-K (ZSK=24, NPER=2112)
    float* partialA = (float*)alloc((size_t)ZSK * 512 * 512 * 4);          // 25.2 MB
    float* partialX = (float*)u;    // 24*512*128*4 = 6.3 MB <= 12.8 MB

    float* outX = (float*)d_out;            // [500][64]
    float* outA = outX + (size_t)K * C;     // [500][500]

    (void)hipMemsetAsync(bcur, 0, (size_t)2 * NBUCK * 4, stream);

    // two-phase binned CSR build
    binA_kernel<<<(E + 1023) / 1024, 256, 0, stream>>>(rowv, colv, bcurC, bcurR,
                                                       bstoreC, bstoreR, E);
    buildcsr_kernel<<<NBUCK, 256, 0, stream>>>(bcurC, bstoreC, esrc, degc, N);
    rowdeg_kernel<<<NBUCK, 256, 0, stream>>>(bcurR, bstoreR, dinv, N);

    // fused prep: xb + WaT + WeT
    {
        int total = N * 16 + (KPAD + DD) * 64;
        prep_kernel<<<(total + 255) / 256, 256, 0, stream>>>(x, dinv, xb, W_assign, W_embed,
                                                             WaT, WeT, N * 16);
    }

    agg_kernel<<<NPAD / 4, 256, 0, stream>>>(xb, dinv, degc, esrc, tsum, ubuf, N);

    fused_s3_kernel<<<NPAD / 16, 256, 0, stream>>>(ubuf, WaT, WeT, b_assign, b_embed,
                                                   dinv, tsum, S_T, Sf8, Z_T, N);

    g_agg_t_kernel<<<NPAD / GT_ROWS, 512, 0, stream>>>(Sf8, degc, esrc, G_T, N);

    // combined GEMM: next_A (tiles 0..15) + next_X (tiles 16..19), z-grouped XCD swizzle
    mfma_comb_kernel<<<20 * ZSK, 256, 0, stream>>>(S_T, G_T, Z_T, partialA, partialX);

    // combined reduce
    {
        int total = K * C + K * K;   // 282000
        reduce2_kernel<<<(total + 255) / 256, 256, 0, stream>>>(partialX, partialA, outX, outA, ZSK);
    }
}